// Round 2
// baseline (57.803 us; speedup 1.0000x reference)
//
#include <hip/hip_runtime.h>
#include <math.h>

// Problem: B=256, D=512, H=512.
// Separable head: pre[i,j,h] = A'[j,h] + C[i,h]
//   A'[j,h] = emb[j,:] @ W1[0:512, h] + b1[h]
//   C [i,h] = emb[i,:] @ W1[512:1024, h]
// loss[i,j] = BCE(labels[i]==labels[j], sigmoid(sum_h relu(A'+C)*w2[h] + b2))

#define B 256
#define D 512
#define H 512

// ---------------- Kernel 1: A' and C (fp32, scalar-emb x vector-W1) --------
// grid: (2 col-halves, 32 row-groups, 2 matrices), block: 256.
// emb accesses are wave-uniform -> s_load (scalar pipe); W1 accesses are
// lane-consecutive in h -> coalesced vector loads. No LDS at all.
__global__ __launch_bounds__(256) void head_gemm(
    const float* __restrict__ emb, const float* __restrict__ W1,
    const float* __restrict__ b1, float* __restrict__ A, float* __restrict__ C) {
    const int z  = blockIdx.z;              // 0: A' (top half of W1), 1: C
    const int r0 = blockIdx.y * 8;          // first emb row of this block
    const int h  = blockIdx.x * 256 + threadIdx.x;  // output column

    float acc[8];
    const float binit = z ? 0.0f : b1[h];
#pragma unroll
    for (int r = 0; r < 8; ++r) acc[r] = binit;

    const float* w = W1 + (size_t)(z * D) * H + h;  // column h, stride H per d
    const float* e = emb + (size_t)r0 * D;          // 8 rows, wave-uniform

#pragma unroll 2
    for (int d = 0; d < D; d += 8) {
        float wv[8];
#pragma unroll
        for (int k = 0; k < 8; ++k)
            wv[k] = w[(size_t)(d + k) * H];         // vector, coalesced
#pragma unroll
        for (int r = 0; r < 8; ++r) {
#pragma unroll
            for (int k = 0; k < 8; ++k)
                acc[r] = fmaf(e[r * D + d + k], wv[k], acc[r]);  // s_load * vgpr
        }
    }

    float* dst = z ? C : A;
#pragma unroll
    for (int r = 0; r < 8; ++r) dst[(size_t)(r0 + r) * H + h] = acc[r];
}

// ---------------- Kernel 2: pairwise relu-dot + BCE ------------------------
// 16x16 pair tile per block, 128 threads, 2 outputs/thread (i and i+8).
// Reads per 4-h step: 1x a (float4) + 2x c (float4) from LDS for 2 outputs;
// w2 is wave-uniform -> scalar loads. Grid (16,16) = 256 blocks = 1/CU.
#define PADH 516  // +4 floats: row-start bank = 4*r mod 32 -> 2-way only (free)

__global__ __launch_bounds__(128) void pair_loss(
    const float* __restrict__ A, const float* __restrict__ C,
    const float* __restrict__ w2, const float* __restrict__ b2,
    const int* __restrict__ labels, float* __restrict__ out) {
    __shared__ float sA[16][PADH];
    __shared__ float sC[16][PADH];

    const int j0 = blockIdx.x * 16;
    const int i0 = blockIdx.y * 16;
    const int tid = threadIdx.x;

    // Stage 16 rows of A' (j-tile) and 16 rows of C (i-tile); rows contiguous.
    for (int idx = tid; idx < 16 * (H / 4); idx += 128) {
        const int r = idx >> 7;          // H/4 = 128 float4 per row
        const int c4 = idx & 127;
        float4 va = ((const float4*)(A + (size_t)(j0 + r) * H))[c4];
        *(float4*)&sA[r][c4 * 4] = va;
        float4 vc = ((const float4*)(C + (size_t)(i0 + r) * H))[c4];
        *(float4*)&sC[r][c4 * 4] = vc;
    }
    __syncthreads();

    const int tx = tid & 15;   // j within tile
    const int ty = tid >> 4;   // i within tile: rows ty and ty+8

    float s0 = 0.0f, s1 = 0.0f;
#pragma unroll 4
    for (int h = 0; h < H; h += 4) {
        float4 a  = *(const float4*)&sA[tx][h];
        float4 c0 = *(const float4*)&sC[ty][h];
        float4 c1 = *(const float4*)&sC[ty + 8][h];
        float4 w  = *(const float4*)&w2[h];   // wave-uniform -> s_load
        s0 = fmaf(fmaxf(a.x + c0.x, 0.0f), w.x, s0);
        s0 = fmaf(fmaxf(a.y + c0.y, 0.0f), w.y, s0);
        s0 = fmaf(fmaxf(a.z + c0.z, 0.0f), w.z, s0);
        s0 = fmaf(fmaxf(a.w + c0.w, 0.0f), w.w, s0);
        s1 = fmaf(fmaxf(a.x + c1.x, 0.0f), w.x, s1);
        s1 = fmaf(fmaxf(a.y + c1.y, 0.0f), w.y, s1);
        s1 = fmaf(fmaxf(a.z + c1.z, 0.0f), w.z, s1);
        s1 = fmaf(fmaxf(a.w + c1.w, 0.0f), w.w, s1);
    }

    const float bias = b2[0];
    const int j = j0 + tx;
    const int lj = labels[j];

#pragma unroll
    for (int q = 0; q < 2; ++q) {
        const int i = i0 + ty + q * 8;
        const float z = (q ? s1 : s0) + bias;
        float p = 1.0f / (1.0f + expf(-z));
        p = fminf(fmaxf(p, 1e-7f), 1.0f - 1e-7f);
        const float t = (labels[i] == lj) ? 1.0f : 0.0f;
        const float loss = -(t * logf(p) + (1.0f - t) * log1pf(-p));
        out[(size_t)i * B + j] = loss;
    }
}

extern "C" void kernel_launch(void* const* d_in, const int* in_sizes, int n_in,
                              void* d_out, int out_size, void* d_ws, size_t ws_size,
                              hipStream_t stream) {
    const float* emb    = (const float*)d_in[0];
    const int*   labels = (const int*)d_in[1];
    const float* W1     = (const float*)d_in[2];
    const float* b1     = (const float*)d_in[3];
    const float* W2     = (const float*)d_in[4];
    const float* b2     = (const float*)d_in[5];
    float* out = (float*)d_out;

    float* A = (float*)d_ws;                 // 256*512 floats
    float* C = A + (size_t)B * H;            // 256*512 floats (total 1 MiB)

    dim3 g1(2, 32, 2);
    head_gemm<<<g1, 256, 0, stream>>>(emb, W1, b1, A, C);

    dim3 g2(16, 16);
    pair_loss<<<g2, 128, 0, stream>>>(A, C, W2, b2, labels, out);
}

// Round 3
// 33.939 us; speedup vs baseline: 1.7031x; 1.7031x over previous
//
#include <hip/hip_runtime.h>
#include <math.h>

// Problem: B=256, D=512, H=512.
// Separable head: pre[i,j,h] = A'[j,h] + C[i,h]
//   A'[j,h] = emb[j,:] @ W1[0:512, h] + b1[h]
//   C [i,h] = emb[i,:] @ W1[512:1024, h]
// loss[i,j] = BCE(labels[i]==labels[j], sigmoid(sum_h relu(A'+C)*w2[h] + b2))
//
// Round-2: K-split=4 for TLP (512 blocks, 8 waves/CU), partials in d_ws,
// reduction folded into pair_loss staging. Round-1's scalar-emb experiment
// regressed (s_load serialization) -> back to LDS-broadcast inner loop.

#define B 256
#define D 512
#define H 512
#define KS 4
#define DC (D / KS)   // 128 d-values per partial block

// ---------------- Kernel 1: partial GEMM -----------------------------------
// grid: x = 2(col-half) * 4(ks) = 8, y = 32 (row-groups of 8), z = 2 (A'/C)
// Partial layout: P[ks][z][row][h]  (each partial slab is 2*B*H floats)
__global__ __launch_bounds__(256) void head_partial(
    const float* __restrict__ emb, const float* __restrict__ W1,
    const float* __restrict__ b1, float* __restrict__ P) {
    __shared__ float sE[8 * DC];  // 4 KiB: 8 rows x 128 d

    const int colhalf = blockIdx.x & 1;
    const int ks      = blockIdx.x >> 1;
    const int r0      = blockIdx.y * 8;
    const int z       = blockIdx.z;
    const int h       = colhalf * 256 + threadIdx.x;
    const int d0      = ks * DC;

    // Stage 8 rows x 128 d: one float4 per thread.
    {
        const int r = threadIdx.x >> 5;
        const int c4 = threadIdx.x & 31;
        *(float4*)&sE[r * DC + c4 * 4] =
            *(const float4*)&emb[(size_t)(r0 + r) * D + d0 + c4 * 4];
    }
    __syncthreads();

    float acc[8];
    const float binit = (z == 0 && ks == 0) ? b1[h] : 0.0f;
#pragma unroll
    for (int r = 0; r < 8; ++r) acc[r] = binit;

    const float* w = W1 + (size_t)(z * D + d0) * H + h;  // col h, stride H per d

    // Register double-buffered strided W1 loads (4 per step).
    float cur0 = w[0 * (size_t)H], cur1 = w[1 * (size_t)H];
    float cur2 = w[2 * (size_t)H], cur3 = w[3 * (size_t)H];
#pragma unroll 4
    for (int d = 0; d < DC; d += 4) {
        const int dn = (d + 4) & (DC - 1);  // wraps to 0 on last iter (valid addr)
        const float n0 = w[(size_t)(dn + 0) * H];
        const float n1 = w[(size_t)(dn + 1) * H];
        const float n2 = w[(size_t)(dn + 2) * H];
        const float n3 = w[(size_t)(dn + 3) * H];
#pragma unroll
        for (int r = 0; r < 8; ++r) {
            float4 e = *(const float4*)&sE[r * DC + d];  // wave-uniform broadcast
            acc[r] = fmaf(e.x, cur0, acc[r]);
            acc[r] = fmaf(e.y, cur1, acc[r]);
            acc[r] = fmaf(e.z, cur2, acc[r]);
            acc[r] = fmaf(e.w, cur3, acc[r]);
        }
        cur0 = n0; cur1 = n1; cur2 = n2; cur3 = n3;
    }

    float* dst = P + ((size_t)(ks * 2 + z) * B + r0) * H + h;
#pragma unroll
    for (int r = 0; r < 8; ++r) dst[(size_t)r * H] = acc[r];
}

// ---------------- Kernel 2: partial-sum staging + pairwise relu-dot + BCE --
// 16x16 pair tile, 128 threads, 2 outputs/thread (round-1-proven structure).
#define PADH 516  // row-start bank = 4*r mod 32 -> only 2-way aliasing (free)

__global__ __launch_bounds__(128) void pair_loss(
    const float* __restrict__ P, const float* __restrict__ w2,
    const float* __restrict__ b2, const int* __restrict__ labels,
    float* __restrict__ out) {
    __shared__ float sA[16][PADH];
    __shared__ float sC[16][PADH];

    const int j0 = blockIdx.x * 16;
    const int i0 = blockIdx.y * 16;
    const int tid = threadIdx.x;
    const size_t KSTR = (size_t)2 * B * H;  // floats between ks-partials

    // Stage 16 rows of A' (j-tile) and C (i-tile), summing the 4 partials.
    for (int idx = tid; idx < 16 * (H / 4); idx += 128) {
        const int r = idx >> 7;          // H/4 = 128 float4 per row
        const int c4 = idx & 127;
        const float* pa = P + (size_t)(j0 + r) * H + c4 * 4;        // z=0 slab
        const float* pc = P + (size_t)(B + i0 + r) * H + c4 * 4;    // z=1 slab
        float4 a0 = *(const float4*)(pa);
        float4 a1 = *(const float4*)(pa + KSTR);
        float4 a2 = *(const float4*)(pa + 2 * KSTR);
        float4 a3 = *(const float4*)(pa + 3 * KSTR);
        float4 c0 = *(const float4*)(pc);
        float4 c1 = *(const float4*)(pc + KSTR);
        float4 c2 = *(const float4*)(pc + 2 * KSTR);
        float4 c3 = *(const float4*)(pc + 3 * KSTR);
        float4 va, vc;
        va.x = (a0.x + a1.x) + (a2.x + a3.x);
        va.y = (a0.y + a1.y) + (a2.y + a3.y);
        va.z = (a0.z + a1.z) + (a2.z + a3.z);
        va.w = (a0.w + a1.w) + (a2.w + a3.w);
        vc.x = (c0.x + c1.x) + (c2.x + c3.x);
        vc.y = (c0.y + c1.y) + (c2.y + c3.y);
        vc.z = (c0.z + c1.z) + (c2.z + c3.z);
        vc.w = (c0.w + c1.w) + (c2.w + c3.w);
        *(float4*)&sA[r][c4 * 4] = va;
        *(float4*)&sC[r][c4 * 4] = vc;
    }
    __syncthreads();

    const int tx = tid & 15;   // j within tile
    const int ty = tid >> 4;   // i within tile: rows ty and ty+8

    float s0 = 0.0f, s1 = 0.0f;
#pragma unroll 4
    for (int h = 0; h < H; h += 4) {
        float4 a  = *(const float4*)&sA[tx][h];
        float4 c0 = *(const float4*)&sC[ty][h];
        float4 c1 = *(const float4*)&sC[ty + 8][h];
        float4 w  = *(const float4*)&w2[h];   // wave-uniform -> s_load
        s0 = fmaf(fmaxf(a.x + c0.x, 0.0f), w.x, s0);
        s0 = fmaf(fmaxf(a.y + c0.y, 0.0f), w.y, s0);
        s0 = fmaf(fmaxf(a.z + c0.z, 0.0f), w.z, s0);
        s0 = fmaf(fmaxf(a.w + c0.w, 0.0f), w.w, s0);
        s1 = fmaf(fmaxf(a.x + c1.x, 0.0f), w.x, s1);
        s1 = fmaf(fmaxf(a.y + c1.y, 0.0f), w.y, s1);
        s1 = fmaf(fmaxf(a.z + c1.z, 0.0f), w.z, s1);
        s1 = fmaf(fmaxf(a.w + c1.w, 0.0f), w.w, s1);
    }

    const float bias = b2[0];
    const int j = j0 + tx;
    const int lj = labels[j];

#pragma unroll
    for (int q = 0; q < 2; ++q) {
        const int i = i0 + ty + q * 8;
        const float z = (q ? s1 : s0) + bias;
        float p = 1.0f / (1.0f + expf(-z));
        p = fminf(fmaxf(p, 1e-7f), 1.0f - 1e-7f);
        const float t = (labels[i] == lj) ? 1.0f : 0.0f;
        const float loss = -(t * logf(p) + (1.0f - t) * log1pf(-p));
        out[(size_t)i * B + j] = loss;
    }
}

extern "C" void kernel_launch(void* const* d_in, const int* in_sizes, int n_in,
                              void* d_out, int out_size, void* d_ws, size_t ws_size,
                              hipStream_t stream) {
    const float* emb    = (const float*)d_in[0];
    const int*   labels = (const int*)d_in[1];
    const float* W1     = (const float*)d_in[2];
    const float* b1     = (const float*)d_in[3];
    const float* W2     = (const float*)d_in[4];
    const float* b2     = (const float*)d_in[5];
    float* out = (float*)d_out;

    float* P = (float*)d_ws;   // KS * 2 * B * H floats = 4 MiB of partials

    dim3 g1(2 * KS, 32, 2);
    head_partial<<<g1, 256, 0, stream>>>(emb, W1, b1, P);

    dim3 g2(16, 16);
    pair_loss<<<g2, 128, 0, stream>>>(P, W2, b2, labels, out);
}